// Round 1
// baseline (1742.111 us; speedup 1.0000x reference)
//
#include <hip/hip_runtime.h>
#include <math.h>

// Problem constants (from reference)
#define BB    256
#define NMAX  512
#define HH    256   // H
#define CC    64    // C
#define HID   512
#define DD_N  511   // D = NMAX-1
#define NEGV  -1000000000.0f
#define TD    16    // d-rows per block in mlp kernel

// ---------------------------------------------------------------------------
// Kernel 1: per-batch base vector v_b[j] = b1[j] + src @ W1[srcoff..] + cc @ W1[512..]
// grid = B, block = 256 (each thread computes j=2t, 2t+1)
// ---------------------------------------------------------------------------
__global__ __launch_bounds__(256) void base_kernel(
    const float* __restrict__ nodes_hv, const float* __restrict__ class_cond,
    const float* __restrict__ W1, const float* __restrict__ b1,
    const int* __restrict__ dirns, const int* __restrict__ node_counts,
    float* __restrict__ v_ws)
{
    const int b = blockIdx.x;
    const int t = threadIdx.x;
    __shared__ float s_src[HH];
    __shared__ float s_cc[CC];

    const int nc   = node_counts[b];
    const int dirn = dirns[b];
    const int src_idx = nc - 1;

    // stage src embedding (H=256 floats) and class_cond (64 floats)
    s_src[t] = nodes_hv[((size_t)b * NMAX + src_idx) * HH + t];
    if (t < CC) s_cc[t] = class_cond[b * CC + t];
    __syncthreads();

    // dirn==1: x = [cand, src, cc]  -> src uses W1 rows [256:512)
    // dirn==0: x = [src, cand, cc]  -> src uses W1 rows [0:256)
    const int srcoff = (dirn == 1) ? HH : 0;

    const int j = 2 * t;
    float acc0 = b1[j];
    float acc1 = b1[j + 1];

    #pragma unroll 4
    for (int r = 0; r < HH; ++r) {
        const float s = s_src[r];
        const float* wp = W1 + (size_t)(srcoff + r) * HID + j;
        acc0 += s * wp[0];
        acc1 += s * wp[1];
    }
    #pragma unroll 4
    for (int c = 0; c < CC; ++c) {
        const float s = s_cc[c];
        const float* wp = W1 + (size_t)(2 * HH + c) * HID + j;
        acc0 += s * wp[0];
        acc1 += s * wp[1];
    }
    v_ws[b * HID + j]     = acc0;
    v_ws[b * HID + j + 1] = acc1;
}

// ---------------------------------------------------------------------------
// Kernel 2: fused MLP over a tile of TD=16 candidate rows of one batch.
// grid = (NMAX/TD, B), block = 256. Each thread owns columns j=2t, 2t+1.
// scores[b*NMAX + d] written for all d in [0,512); invalid -> NEG.
// ---------------------------------------------------------------------------
__global__ __launch_bounds__(256) void mlp_kernel(
    const float* __restrict__ nodes_hv,
    const float* __restrict__ W1, const float* __restrict__ W2,
    const float* __restrict__ b2, const float* __restrict__ W3,
    const float* __restrict__ b3,
    const int* __restrict__ dirns, const int* __restrict__ node_counts,
    const float* __restrict__ v_ws, float* __restrict__ scores)
{
    const int b  = blockIdx.y;
    const int d0 = blockIdx.x * TD;
    const int t  = threadIdx.x;

    __shared__ float s_x[TD * HH];    // 16 KiB: cand tile (fp32)
    __shared__ float s_v[HID];        // 2 KiB
    __shared__ float s_h[TD * HID];   // 32 KiB: h1 tile
    __shared__ float s_red[TD][4];

    const int nc   = node_counts[b];
    const int dirn = dirns[b];
    // dirn==1: cand occupies x[0:256) -> W1 rows [0:256); else rows [256:512)
    const int candoff = (dirn == 1) ? 0 : HH;

    // stage cand tile (TD*H = 4096 floats) with float4 loads
    {
        const float4* src = (const float4*)(nodes_hv + ((size_t)b * NMAX + d0) * HH);
        float4* dst = (float4*)s_x;
        #pragma unroll
        for (int i = 0; i < (TD * HH / 4) / 256; ++i)
            dst[t + i * 256] = src[t + i * 256];
    }
    s_v[t]       = v_ws[b * HID + t];
    s_v[t + 256] = v_ws[b * HID + t + 256];
    __syncthreads();

    const int j = 2 * t;

    // ---- layer 1: acc[dd] = cand[dd] @ W1cand[:, j..j+1] ----
    float acc0[TD], acc1[TD];
    #pragma unroll
    for (int dd = 0; dd < TD; ++dd) { acc0[dd] = 0.f; acc1[dd] = 0.f; }

    for (int r = 0; r < HH; r += 4) {
        const float* wp = W1 + (size_t)(candoff + r) * HID + j;
        const float2 w0 = *(const float2*)(wp);
        const float2 w1 = *(const float2*)(wp + HID);
        const float2 w2 = *(const float2*)(wp + 2 * HID);
        const float2 w3 = *(const float2*)(wp + 3 * HID);
        #pragma unroll
        for (int dd = 0; dd < TD; ++dd) {
            const float4 c = *(const float4*)&s_x[dd * HH + r];
            acc0[dd] += c.x * w0.x + c.y * w1.x + c.z * w2.x + c.w * w3.x;
            acc1[dd] += c.x * w0.y + c.y * w1.y + c.z * w2.y + c.w * w3.y;
        }
    }

    // h1 = relu(acc + v), into LDS
    {
        const float v0 = s_v[j], v1 = s_v[j + 1];
        #pragma unroll
        for (int dd = 0; dd < TD; ++dd) {
            float h0 = acc0[dd] + v0;
            float h1 = acc1[dd] + v1;
            h0 = h0 > 0.f ? h0 : 0.f;
            h1 = h1 > 0.f ? h1 : 0.f;
            *(float2*)&s_h[dd * HID + j] = make_float2(h0, h1);
        }
    }
    __syncthreads();

    // ---- layer 2: acc[dd] = h1[dd] @ W2[:, j..j+1] ----
    #pragma unroll
    for (int dd = 0; dd < TD; ++dd) { acc0[dd] = 0.f; acc1[dd] = 0.f; }

    for (int r = 0; r < HID; r += 4) {
        const float* wp = W2 + (size_t)r * HID + j;
        const float2 w0 = *(const float2*)(wp);
        const float2 w1 = *(const float2*)(wp + HID);
        const float2 w2 = *(const float2*)(wp + 2 * HID);
        const float2 w3 = *(const float2*)(wp + 3 * HID);
        #pragma unroll
        for (int dd = 0; dd < TD; ++dd) {
            const float4 c = *(const float4*)&s_h[dd * HID + r];
            acc0[dd] += c.x * w0.x + c.y * w1.x + c.z * w2.x + c.w * w3.x;
            acc1[dd] += c.x * w0.y + c.y * w1.y + c.z * w2.y + c.w * w3.y;
        }
    }

    // ---- layer 3: score partials p[dd] = relu(acc+b2) . W3 ----
    const float bb0 = b2[j], bb1 = b2[j + 1];
    const float w3a = W3[j], w3b = W3[j + 1];
    float p[TD];
    #pragma unroll
    for (int dd = 0; dd < TD; ++dd) {
        float h0 = acc0[dd] + bb0;
        float h1 = acc1[dd] + bb1;
        h0 = h0 > 0.f ? h0 : 0.f;
        h1 = h1 > 0.f ? h1 : 0.f;
        p[dd] = h0 * w3a + h1 * w3b;
    }

    // block reduction: wave shuffle then 4-wave combine in LDS
    const int lane = t & 63, wv = t >> 6;
    #pragma unroll
    for (int dd = 0; dd < TD; ++dd) {
        float v = p[dd];
        #pragma unroll
        for (int off = 32; off > 0; off >>= 1) v += __shfl_down(v, off, 64);
        if (lane == 0) s_red[dd][wv] = v;
    }
    __syncthreads();
    if (t < TD) {
        const float s = s_red[t][0] + s_red[t][1] + s_red[t][2] + s_red[t][3] + b3[0];
        const int d = d0 + t;
        scores[b * NMAX + d] = (d < nc - 1) ? s : NEGV;
    }
}

// ---------------------------------------------------------------------------
// Kernel 3: per-batch masked log-softmax NLL. grid = B, block = 256.
// ---------------------------------------------------------------------------
__global__ __launch_bounds__(256) void loss_kernel(
    const float* __restrict__ scores, const int* __restrict__ dests,
    float* __restrict__ out)
{
    const int b = blockIdx.x;
    const int t = threadIdx.x;
    __shared__ float red[4];

    const float s0 = scores[b * NMAX + t];
    const float s1 = scores[b * NMAX + t + 256];

    const int lane = t & 63, wv = t >> 6;

    float mx = fmaxf(s0, s1);
    #pragma unroll
    for (int off = 32; off > 0; off >>= 1) mx = fmaxf(mx, __shfl_down(mx, off, 64));
    if (lane == 0) red[wv] = mx;
    __syncthreads();
    mx = fmaxf(fmaxf(red[0], red[1]), fmaxf(red[2], red[3]));
    __syncthreads();

    float e = __expf(s0 - mx) + __expf(s1 - mx);
    #pragma unroll
    for (int off = 32; off > 0; off >>= 1) e += __shfl_down(e, off, 64);
    if (lane == 0) red[wv] = e;
    __syncthreads();

    if (t == 0) {
        const float sum = red[0] + red[1] + red[2] + red[3];
        const float sd = scores[b * NMAX + dests[b]];
        out[b] = -(sd - mx - logf(sum));
    }
}

// ---------------------------------------------------------------------------
extern "C" void kernel_launch(void* const* d_in, const int* in_sizes, int n_in,
                              void* d_out, int out_size, void* d_ws, size_t ws_size,
                              hipStream_t stream) {
    const float* nodes_hv   = (const float*)d_in[0];
    const float* class_cond = (const float*)d_in[1];
    const float* W1         = (const float*)d_in[2];
    const float* b1         = (const float*)d_in[3];
    const float* W2         = (const float*)d_in[4];
    const float* b2         = (const float*)d_in[5];
    const float* W3         = (const float*)d_in[6];
    const float* b3         = (const float*)d_in[7];
    const int*   dirns      = (const int*)d_in[8];
    const int*   node_counts= (const int*)d_in[9];
    const int*   dests      = (const int*)d_in[10];
    float* out = (float*)d_out;

    // ws layout: [v_ws: B*HID floats][scores: B*NMAX floats] = 1 MiB total
    float* v_ws   = (float*)d_ws;
    float* scores = v_ws + BB * HID;

    base_kernel<<<BB, 256, 0, stream>>>(nodes_hv, class_cond, W1, b1,
                                        dirns, node_counts, v_ws);
    mlp_kernel<<<dim3(NMAX / TD, BB), 256, 0, stream>>>(
        nodes_hv, W1, W2, b2, W3, b3, dirns, node_counts, v_ws, scores);
    loss_kernel<<<BB, 256, 0, stream>>>(scores, dests, out);
}

// Round 2
// 593.626 us; speedup vs baseline: 2.9347x; 2.9347x over previous
//
#include <hip/hip_runtime.h>
#include <math.h>

// Problem constants
#define BB    256
#define NMAX  512
#define HH    256   // H
#define CC    64    // C
#define HID   512
#define NEGV  -1000000000.0f
#define MT    32    // d-rows per mlp block
#define SA_LD 264   // 256 + 8 pad (bf16 elems) -> 2-way-free LDS bank pattern
#define SH_LD 520   // 512 + 8 pad

typedef __attribute__((ext_vector_type(8))) short short8;   // 8 bf16 = 4 VGPRs
typedef __attribute__((ext_vector_type(4))) float floatx4;  // MFMA C/D

__device__ inline ushort f2bf(float x) {
    unsigned u = __float_as_uint(x);
    u = (u + 0x7FFFu + ((u >> 16) & 1u)) >> 16;   // RNE
    return (ushort)u;
}

// ---------------------------------------------------------------------------
// One-time: W1 (576x512 fp32, row-major [k][n]) -> Wt1 (bf16, [n][k] = 512x576)
// ---------------------------------------------------------------------------
__global__ __launch_bounds__(256) void convert_W1(const float* __restrict__ W1,
                                                  ushort* __restrict__ Wt1) {
    int idx = blockIdx.x * 256 + threadIdx.x;    // over 512*576
    int n = idx / 576, k = idx - n * 576;
    Wt1[idx] = f2bf(W1[k * HID + n]);
}

// W2 (512x512) -> Wt2 (bf16, [n][k])
__global__ __launch_bounds__(256) void convert_W2(const float* __restrict__ W2,
                                                  ushort* __restrict__ Wt2) {
    int idx = blockIdx.x * 256 + threadIdx.x;    // over 512*512
    int n = idx >> 9, k = idx & 511;
    Wt2[idx] = f2bf(W2[k * HID + n]);
}

// ---------------------------------------------------------------------------
// Kernel 1: per-batch base vector v_b = b1 + src @ W1[srcoff] + cc @ W1[512..]
// (fp32, tiny). grid = B, block = 256; thread computes j=2t, 2t+1.
// ---------------------------------------------------------------------------
__global__ __launch_bounds__(256) void base_kernel(
    const float* __restrict__ nodes_hv, const float* __restrict__ class_cond,
    const float* __restrict__ W1, const float* __restrict__ b1,
    const int* __restrict__ dirns, const int* __restrict__ node_counts,
    float* __restrict__ v_ws)
{
    const int b = blockIdx.x;
    const int t = threadIdx.x;
    __shared__ float s_src[HH];
    __shared__ float s_cc[CC];

    const int nc   = node_counts[b];
    const int dirn = dirns[b];
    const int src_idx = nc - 1;

    s_src[t] = nodes_hv[((size_t)b * NMAX + src_idx) * HH + t];
    if (t < CC) s_cc[t] = class_cond[b * CC + t];
    __syncthreads();

    const int srcoff = (dirn == 1) ? HH : 0;   // src rows of W1

    const int j = 2 * t;
    float acc0 = b1[j];
    float acc1 = b1[j + 1];

    #pragma unroll 4
    for (int r = 0; r < HH; ++r) {
        const float s = s_src[r];
        const float* wp = W1 + (size_t)(srcoff + r) * HID + j;
        acc0 += s * wp[0];
        acc1 += s * wp[1];
    }
    #pragma unroll 4
    for (int c = 0; c < CC; ++c) {
        const float s = s_cc[c];
        const float* wp = W1 + (size_t)(2 * HH + c) * HID + j;
        acc0 += s * wp[0];
        acc1 += s * wp[1];
    }
    v_ws[b * HID + j]     = acc0;
    v_ws[b * HID + j + 1] = acc1;
}

// ---------------------------------------------------------------------------
// Kernel 2: MFMA MLP. grid = (NMAX/MT, B), block = 256 (4 waves).
// Wave w owns N-chunk [w*128, w*128+128). Each wave: 2 m-blocks x 8 n-tiles
// of 16x16x32 bf16 MFMA. h1 round-trips through LDS (bf16).
// ---------------------------------------------------------------------------
__global__ __launch_bounds__(256, 3) void mlp2(
    const float* __restrict__ nodes_hv,
    const ushort* __restrict__ Wt1, const ushort* __restrict__ Wt2,
    const float* __restrict__ b2, const float* __restrict__ W3,
    const float* __restrict__ b3,
    const int* __restrict__ dirns, const int* __restrict__ node_counts,
    const float* __restrict__ v_ws, float* __restrict__ scores)
{
    const int b  = blockIdx.y;
    const int d0 = blockIdx.x * MT;
    const int t  = threadIdx.x;
    const int lane = t & 63, wv = t >> 6;
    const int l15 = lane & 15, q = lane >> 4;

    __shared__ ushort s_a[MT * SA_LD];     // cand tile bf16: 16.9 KB
    __shared__ ushort s_h[MT * SH_LD];     // h1 tile bf16:   33.3 KB
    __shared__ float  s_red[4][MT];

    const int nc = node_counts[b];
    // dirn==1: cand occupies x[0:256) -> W1 k-rows [0:256); else [256:512)
    const int candoff = (dirns[b] == 1) ? 0 : HH;

    // ---- stage cand tile (MT x 256 fp32 -> bf16 LDS) ----
    {
        const float4* src4 = (const float4*)nodes_hv + ((size_t)b * NMAX + d0) * (HH / 4);
        #pragma unroll
        for (int i = 0; i < (MT * HH / 4) / 256; ++i) {   // 8 iters
            int idx = t + i * 256;
            int row = idx >> 6, c4 = idx & 63;
            float4 v = src4[idx];
            ushort4 p;
            p.x = f2bf(v.x); p.y = f2bf(v.y); p.z = f2bf(v.z); p.w = f2bf(v.w);
            *(ushort4*)&s_a[row * SA_LD + c4 * 4] = p;
        }
    }
    __syncthreads();

    const int n0 = wv * 128;

    floatx4 acc[2][8];
    #pragma unroll
    for (int mb = 0; mb < 2; ++mb)
        #pragma unroll
        for (int tn = 0; tn < 8; ++tn)
            acc[mb][tn] = (floatx4){0.f, 0.f, 0.f, 0.f};

    // ---- layer 1: K = 256 (8 K-steps of 32) ----
    {
        const ushort* wbase = Wt1 + (size_t)(n0 + l15) * 576 + candoff + q * 8;
        #pragma unroll 2
        for (int ks = 0; ks < 8; ++ks) {
            short8 a0 = *(const short8*)&s_a[l15 * SA_LD + ks * 32 + q * 8];
            short8 a1 = *(const short8*)&s_a[(16 + l15) * SA_LD + ks * 32 + q * 8];
            short8 bf[8];
            #pragma unroll
            for (int tn = 0; tn < 8; ++tn)
                bf[tn] = *(const short8*)(wbase + (size_t)tn * 16 * 576 + ks * 32);
            #pragma unroll
            for (int tn = 0; tn < 8; ++tn) {
                acc[0][tn] = __builtin_amdgcn_mfma_f32_16x16x32_bf16(a0, bf[tn], acc[0][tn], 0, 0, 0);
                acc[1][tn] = __builtin_amdgcn_mfma_f32_16x16x32_bf16(a1, bf[tn], acc[1][tn], 0, 0, 0);
            }
        }
    }

    // ---- epilogue 1: h1 = relu(acc + v_b) -> s_h (bf16) ----
    #pragma unroll
    for (int tn = 0; tn < 8; ++tn) {
        const int n = n0 + tn * 16 + l15;
        const float v = v_ws[b * HID + n];
        #pragma unroll
        for (int mb = 0; mb < 2; ++mb)
            #pragma unroll
            for (int r = 0; r < 4; ++r) {
                float h = acc[mb][tn][r] + v;          // C/D: row=q*4+r, col=l15
                h = h > 0.f ? h : 0.f;
                s_h[(mb * 16 + q * 4 + r) * SH_LD + n] = f2bf(h);
            }
    }
    __syncthreads();

    // ---- layer 2: K = 512 (16 K-steps) ----
    #pragma unroll
    for (int mb = 0; mb < 2; ++mb)
        #pragma unroll
        for (int tn = 0; tn < 8; ++tn)
            acc[mb][tn] = (floatx4){0.f, 0.f, 0.f, 0.f};
    {
        const ushort* wbase = Wt2 + (size_t)(n0 + l15) * HID + q * 8;
        #pragma unroll 2
        for (int ks = 0; ks < 16; ++ks) {
            short8 a0 = *(const short8*)&s_h[l15 * SH_LD + ks * 32 + q * 8];
            short8 a1 = *(const short8*)&s_h[(16 + l15) * SH_LD + ks * 32 + q * 8];
            short8 bf[8];
            #pragma unroll
            for (int tn = 0; tn < 8; ++tn)
                bf[tn] = *(const short8*)(wbase + (size_t)tn * 16 * HID + ks * 32);
            #pragma unroll
            for (int tn = 0; tn < 8; ++tn) {
                acc[0][tn] = __builtin_amdgcn_mfma_f32_16x16x32_bf16(a0, bf[tn], acc[0][tn], 0, 0, 0);
                acc[1][tn] = __builtin_amdgcn_mfma_f32_16x16x32_bf16(a1, bf[tn], acc[1][tn], 0, 0, 0);
            }
        }
    }

    // ---- epilogue 2: p = relu(acc + b2) . W3, reduce over n ----
    float p[2][4] = {{0.f, 0.f, 0.f, 0.f}, {0.f, 0.f, 0.f, 0.f}};
    #pragma unroll
    for (int tn = 0; tn < 8; ++tn) {
        const int n  = n0 + tn * 16 + l15;
        const float bb = b2[n];
        const float w3 = W3[n];
        #pragma unroll
        for (int mb = 0; mb < 2; ++mb)
            #pragma unroll
            for (int r = 0; r < 4; ++r) {
                float h = acc[mb][tn][r] + bb;
                h = h > 0.f ? h : 0.f;
                p[mb][r] += h * w3;
            }
    }
    // reduce across the 16 lanes (same q-group) holding different n
    #pragma unroll
    for (int mb = 0; mb < 2; ++mb)
        #pragma unroll
        for (int r = 0; r < 4; ++r) {
            float v = p[mb][r];
            v += __shfl_xor(v, 1, 64);
            v += __shfl_xor(v, 2, 64);
            v += __shfl_xor(v, 4, 64);
            v += __shfl_xor(v, 8, 64);
            if (l15 == 0) s_red[wv][mb * 16 + q * 4 + r] = v;
        }
    __syncthreads();
    if (t < MT) {
        const float s = s_red[0][t] + s_red[1][t] + s_red[2][t] + s_red[3][t] + b3[0];
        const int d = d0 + t;
        scores[b * NMAX + d] = (d < nc - 1) ? s : NEGV;
    }
}

// ---------------------------------------------------------------------------
// Kernel 3: per-batch masked log-softmax NLL. grid = B, block = 256.
// ---------------------------------------------------------------------------
__global__ __launch_bounds__(256) void loss_kernel(
    const float* __restrict__ scores, const int* __restrict__ dests,
    float* __restrict__ out)
{
    const int b = blockIdx.x;
    const int t = threadIdx.x;
    __shared__ float red[4];

    const float s0 = scores[b * NMAX + t];
    const float s1 = scores[b * NMAX + t + 256];

    const int lane = t & 63, wv = t >> 6;

    float mx = fmaxf(s0, s1);
    #pragma unroll
    for (int off = 32; off > 0; off >>= 1) mx = fmaxf(mx, __shfl_down(mx, off, 64));
    if (lane == 0) red[wv] = mx;
    __syncthreads();
    mx = fmaxf(fmaxf(red[0], red[1]), fmaxf(red[2], red[3]));
    __syncthreads();

    float e = __expf(s0 - mx) + __expf(s1 - mx);
    #pragma unroll
    for (int off = 32; off > 0; off >>= 1) e += __shfl_down(e, off, 64);
    if (lane == 0) red[wv] = e;
    __syncthreads();

    if (t == 0) {
        const float sum = red[0] + red[1] + red[2] + red[3];
        const float sd = scores[b * NMAX + dests[b]];
        out[b] = -(sd - mx - logf(sum));
    }
}

// ---------------------------------------------------------------------------
extern "C" void kernel_launch(void* const* d_in, const int* in_sizes, int n_in,
                              void* d_out, int out_size, void* d_ws, size_t ws_size,
                              hipStream_t stream) {
    const float* nodes_hv    = (const float*)d_in[0];
    const float* class_cond  = (const float*)d_in[1];
    const float* W1          = (const float*)d_in[2];
    const float* b1          = (const float*)d_in[3];
    const float* W2          = (const float*)d_in[4];
    const float* b2          = (const float*)d_in[5];
    const float* W3          = (const float*)d_in[6];
    const float* b3          = (const float*)d_in[7];
    const int*   dirns       = (const int*)d_in[8];
    const int*   node_counts = (const int*)d_in[9];
    const int*   dests       = (const int*)d_in[10];
    float* out = (float*)d_out;

    // ws layout (all 16B-aligned):
    //   Wt1: 512*576 bf16 (576 KiB) | Wt2: 512*512 bf16 (512 KiB)
    //   v_ws: 256*512 fp32 (512 KiB) | scores: 256*512 fp32 (512 KiB)
    ushort* Wt1    = (ushort*)d_ws;
    ushort* Wt2    = Wt1 + 512 * 576;
    float*  v_ws   = (float*)(Wt2 + 512 * 512);
    float*  scores = v_ws + BB * HID;

    convert_W1<<<(512 * 576) / 256, 256, 0, stream>>>(W1, Wt1);
    convert_W2<<<(512 * 512) / 256, 256, 0, stream>>>(W2, Wt2);
    base_kernel<<<BB, 256, 0, stream>>>(nodes_hv, class_cond, W1, b1,
                                        dirns, node_counts, v_ws);
    mlp2<<<dim3(NMAX / MT, BB), 256, 0, stream>>>(
        nodes_hv, Wt1, Wt2, b2, W3, b3, dirns, node_counts, v_ws, scores);
    loss_kernel<<<BB, 256, 0, stream>>>(scores, dests, out);
}

// Round 4
// 355.792 us; speedup vs baseline: 4.8964x; 1.6685x over previous
//
#include <hip/hip_runtime.h>
#include <math.h>

// Problem constants
#define BB    256
#define NMAX  512
#define HH    256   // H
#define CC    64    // C
#define HID   512
#define NEGV  -1000000000.0f
#define MT    32    // d-rows per mlp block
#define SA_LD 264   // 256 + 8 pad (bf16 elems)
#define SH_LD 520   // 512 + 8 pad
#define TILE  512   // ushorts per swizzled (16n x 32k) tile = 1KB
#define KSTR  (32 * TILE)  // ushorts per kb slab (32 n-tiles)

typedef __attribute__((ext_vector_type(8))) short short8;   // 8 bf16 = 4 VGPRs
typedef __attribute__((ext_vector_type(4))) float floatx4;  // MFMA C/D

__device__ inline ushort f2bf(float x) {
    unsigned u = __float_as_uint(x);
    u = (u + 0x7FFFu + ((u >> 16) & 1u)) >> 16;   // RNE
    return (ushort)u;
}

// ---------------------------------------------------------------------------
// Swizzle convert: W (row-major [k][512] fp32) -> lane-order bf16 tiles
//   out[(kb*32 + nt)*512 + lane*8 + j] = bf16(W[kb*32 + (lane>>4)*8 + j][nt*16 + (lane&15)])
// grid = (16 kb, 8 ntg), block = 256. Coalesced reads via LDS transpose.
// ---------------------------------------------------------------------------
__global__ __launch_bounds__(256) void convert_swz(const float* __restrict__ W,
                                                   ushort* __restrict__ out) {
    const int kb = blockIdx.x, ntg = blockIdx.y;
    const int t = threadIdx.x;
    __shared__ float s[32][68];   // 32 k-rows x 64 n (+4 pad)

    {
        const int kl = t >> 3, nn = (t & 7) * 8;
        const float* src = W + (size_t)(kb * 32 + kl) * HID + ntg * 64 + nn;
        *(float4*)&s[kl][nn]     = *(const float4*)src;
        *(float4*)&s[kl][nn + 4] = *(const float4*)(src + 4);
    }
    __syncthreads();

    const int ntl = t >> 6, ls = t & 63;
    const int qs = ls >> 4, l15s = ls & 15;
    short8 o;
    #pragma unroll
    for (int j = 0; j < 8; ++j)
        o[j] = (short)f2bf(s[qs * 8 + j][ntl * 16 + l15s]);
    const int nt = ntg * 4 + ntl;
    *(short8*)(out + ((size_t)(kb * 32 + nt)) * TILE + ls * 8) = o;
}

// ---------------------------------------------------------------------------
// Kernel 1: per-batch base vector v_b = b1 + src @ W1[srcoff] + cc @ W1[512..]
// (fp32 exact, tiny). grid = B, block = 256; thread computes j=2t, 2t+1.
// ---------------------------------------------------------------------------
__global__ __launch_bounds__(256) void base_kernel(
    const float* __restrict__ nodes_hv, const float* __restrict__ class_cond,
    const float* __restrict__ W1, const float* __restrict__ b1,
    const int* __restrict__ dirns, const int* __restrict__ node_counts,
    float* __restrict__ v_ws)
{
    const int b = blockIdx.x;
    const int t = threadIdx.x;
    __shared__ float s_src[HH];
    __shared__ float s_cc[CC];

    const int nc   = node_counts[b];
    const int dirn = dirns[b];
    const int src_idx = nc - 1;

    s_src[t] = nodes_hv[((size_t)b * NMAX + src_idx) * HH + t];
    if (t < CC) s_cc[t] = class_cond[b * CC + t];
    __syncthreads();

    const int srcoff = (dirn == 1) ? HH : 0;   // src rows of W1

    const int j = 2 * t;
    float acc0 = b1[j];
    float acc1 = b1[j + 1];

    #pragma unroll 4
    for (int r = 0; r < HH; ++r) {
        const float s = s_src[r];
        const float* wp = W1 + (size_t)(srcoff + r) * HID + j;
        acc0 += s * wp[0];
        acc1 += s * wp[1];
    }
    #pragma unroll 4
    for (int c = 0; c < CC; ++c) {
        const float s = s_cc[c];
        const float* wp = W1 + (size_t)(2 * HH + c) * HID + j;
        acc0 += s * wp[0];
        acc1 += s * wp[1];
    }
    v_ws[b * HID + j]     = acc0;
    v_ws[b * HID + j + 1] = acc1;
}

// ---------------------------------------------------------------------------
// Kernel 2: MFMA MLP. grid = (NMAX/MT, B), block = 256 (4 waves).
// Wave wv owns N-chunk [wv*128, +128): 2 m-blocks x 8 n-tiles of 16x16x32.
// Plain per-K-step loads (no manual dbuf) from lane-order swizzled weights;
// latency hidden by 3 blocks/CU wave-level overlap. Compiler owns waitcnts.
// ---------------------------------------------------------------------------
__global__ __launch_bounds__(256, 3) void mlp2(
    const float* __restrict__ nodes_hv,
    const ushort* __restrict__ Wt1s, const ushort* __restrict__ Wt2s,
    const float* __restrict__ b2, const float* __restrict__ W3,
    const float* __restrict__ b3,
    const int* __restrict__ dirns, const int* __restrict__ node_counts,
    const float* __restrict__ v_ws, float* __restrict__ scores)
{
    const int b  = blockIdx.y;
    const int d0 = blockIdx.x * MT;
    const int t  = threadIdx.x;
    const int lane = t & 63, wv = t >> 6;
    const int l15 = lane & 15, q = lane >> 4;

    __shared__ ushort s_a[MT * SA_LD];     // cand tile bf16: 16.9 KB
    __shared__ ushort s_h[MT * SH_LD];     // h1 tile bf16:   33.3 KB
    __shared__ float  s_red[4][MT];

    const int nc = node_counts[b];
    // dirn==1: cand occupies x[0:256) -> W1 k-rows [0:256) -> kb0=0; else kb0=8
    const int kb0 = (dirns[b] == 1) ? 0 : 8;

    // ---- stage cand tile (MT x 256 fp32 -> bf16 LDS) ----
    {
        const float4* src4 = (const float4*)nodes_hv + ((size_t)b * NMAX + d0) * (HH / 4);
        #pragma unroll
        for (int i = 0; i < (MT * HH / 4) / 256; ++i) {   // 8 iters
            int idx = t + i * 256;
            int row = idx >> 6, c4 = idx & 63;
            float4 v = src4[idx];
            ushort4 p;
            p.x = f2bf(v.x); p.y = f2bf(v.y); p.z = f2bf(v.z); p.w = f2bf(v.w);
            *(ushort4*)&s_a[row * SA_LD + c4 * 4] = p;
        }
    }
    __syncthreads();

    floatx4 acc[2][8];
    #pragma unroll
    for (int mb = 0; mb < 2; ++mb)
        #pragma unroll
        for (int tn = 0; tn < 8; ++tn)
            acc[mb][tn] = (floatx4){0.f, 0.f, 0.f, 0.f};

    // ---- layer 1: K = 256 (8 K-steps of 32) ----
    {
        const ushort* wb1 = Wt1s + ((size_t)kb0 * 32 + wv * 8) * TILE + lane * 8;
        #pragma unroll
        for (int ks = 0; ks < 8; ++ks) {
            const ushort* wp = wb1 + (size_t)ks * KSTR;
            short8 bfr[8];
            #pragma unroll
            for (int tn = 0; tn < 8; ++tn)
                bfr[tn] = *(const short8*)(wp + tn * TILE);
            short8 a0 = *(const short8*)&s_a[l15 * SA_LD + ks * 32 + q * 8];
            short8 a1 = *(const short8*)&s_a[(16 + l15) * SA_LD + ks * 32 + q * 8];
            #pragma unroll
            for (int tn = 0; tn < 8; ++tn) {
                acc[0][tn] = __builtin_amdgcn_mfma_f32_16x16x32_bf16(a0, bfr[tn], acc[0][tn], 0, 0, 0);
                acc[1][tn] = __builtin_amdgcn_mfma_f32_16x16x32_bf16(a1, bfr[tn], acc[1][tn], 0, 0, 0);
            }
        }
    }

    const int n0 = wv * 128;

    // ---- epilogue 1: h1 = relu(acc + v_b) -> s_h (bf16) ----
    #pragma unroll
    for (int tn = 0; tn < 8; ++tn) {
        const int n = n0 + tn * 16 + l15;
        const float v = v_ws[b * HID + n];
        #pragma unroll
        for (int mb = 0; mb < 2; ++mb)
            #pragma unroll
            for (int r = 0; r < 4; ++r) {
                float h = acc[mb][tn][r] + v;          // C/D: row=q*4+r, col=l15
                h = h > 0.f ? h : 0.f;
                s_h[(mb * 16 + q * 4 + r) * SH_LD + n] = f2bf(h);
            }
    }
    __syncthreads();

    // ---- layer 2: K = 512 (16 K-steps) ----
    #pragma unroll
    for (int mb = 0; mb < 2; ++mb)
        #pragma unroll
        for (int tn = 0; tn < 8; ++tn)
            acc[mb][tn] = (floatx4){0.f, 0.f, 0.f, 0.f};
    {
        const ushort* wb2 = Wt2s + ((size_t)wv * 8) * TILE + lane * 8;
        #pragma unroll
        for (int ks = 0; ks < 16; ++ks) {
            const ushort* wp = wb2 + (size_t)ks * KSTR;
            short8 bfr[8];
            #pragma unroll
            for (int tn = 0; tn < 8; ++tn)
                bfr[tn] = *(const short8*)(wp + tn * TILE);
            short8 a0 = *(const short8*)&s_h[l15 * SH_LD + ks * 32 + q * 8];
            short8 a1 = *(const short8*)&s_h[(16 + l15) * SH_LD + ks * 32 + q * 8];
            #pragma unroll
            for (int tn = 0; tn < 8; ++tn) {
                acc[0][tn] = __builtin_amdgcn_mfma_f32_16x16x32_bf16(a0, bfr[tn], acc[0][tn], 0, 0, 0);
                acc[1][tn] = __builtin_amdgcn_mfma_f32_16x16x32_bf16(a1, bfr[tn], acc[1][tn], 0, 0, 0);
            }
        }
    }

    // ---- epilogue 2: p = relu(acc + b2) . W3, reduce over n ----
    float p[2][4] = {{0.f, 0.f, 0.f, 0.f}, {0.f, 0.f, 0.f, 0.f}};
    #pragma unroll
    for (int tn = 0; tn < 8; ++tn) {
        const int n  = n0 + tn * 16 + l15;
        const float bb = b2[n];
        const float w3 = W3[n];
        #pragma unroll
        for (int mb = 0; mb < 2; ++mb)
            #pragma unroll
            for (int r = 0; r < 4; ++r) {
                float h = acc[mb][tn][r] + bb;
                h = h > 0.f ? h : 0.f;
                p[mb][r] += h * w3;
            }
    }
    #pragma unroll
    for (int mb = 0; mb < 2; ++mb)
        #pragma unroll
        for (int r = 0; r < 4; ++r) {
            float v = p[mb][r];
            v += __shfl_xor(v, 1, 64);
            v += __shfl_xor(v, 2, 64);
            v += __shfl_xor(v, 4, 64);
            v += __shfl_xor(v, 8, 64);
            if (l15 == 0) s_red[wv][mb * 16 + q * 4 + r] = v;
        }
    __syncthreads();
    if (t < MT) {
        const float s = s_red[0][t] + s_red[1][t] + s_red[2][t] + s_red[3][t] + b3[0];
        const int d = d0 + t;
        scores[b * NMAX + d] = (d < nc - 1) ? s : NEGV;
    }
}

// ---------------------------------------------------------------------------
// Kernel 3: per-batch masked log-softmax NLL. grid = B, block = 256.
// ---------------------------------------------------------------------------
__global__ __launch_bounds__(256) void loss_kernel(
    const float* __restrict__ scores, const int* __restrict__ dests,
    float* __restrict__ out)
{
    const int b = blockIdx.x;
    const int t = threadIdx.x;
    __shared__ float red[4];

    const float s0 = scores[b * NMAX + t];
    const float s1 = scores[b * NMAX + t + 256];

    const int lane = t & 63, wv = t >> 6;

    float mx = fmaxf(s0, s1);
    #pragma unroll
    for (int off = 32; off > 0; off >>= 1) mx = fmaxf(mx, __shfl_down(mx, off, 64));
    if (lane == 0) red[wv] = mx;
    __syncthreads();
    mx = fmaxf(fmaxf(red[0], red[1]), fmaxf(red[2], red[3]));
    __syncthreads();

    float e = __expf(s0 - mx) + __expf(s1 - mx);
    #pragma unroll
    for (int off = 32; off > 0; off >>= 1) e += __shfl_down(e, off, 64);
    if (lane == 0) red[wv] = e;
    __syncthreads();

    if (t == 0) {
        const float sum = red[0] + red[1] + red[2] + red[3];
        const float sd = scores[b * NMAX + dests[b]];
        out[b] = -(sd - mx - logf(sum));
    }
}

// ---------------------------------------------------------------------------
extern "C" void kernel_launch(void* const* d_in, const int* in_sizes, int n_in,
                              void* d_out, int out_size, void* d_ws, size_t ws_size,
                              hipStream_t stream) {
    const float* nodes_hv    = (const float*)d_in[0];
    const float* class_cond  = (const float*)d_in[1];
    const float* W1          = (const float*)d_in[2];
    const float* b1          = (const float*)d_in[3];
    const float* W2          = (const float*)d_in[4];
    const float* b2          = (const float*)d_in[5];
    const float* W3          = (const float*)d_in[6];
    const float* b3          = (const float*)d_in[7];
    const int*   dirns       = (const int*)d_in[8];
    const int*   node_counts = (const int*)d_in[9];
    const int*   dests       = (const int*)d_in[10];
    float* out = (float*)d_out;

    // ws layout (16B-aligned):
    //   Wt1s: 512 tiles * 1KB (512 KiB) | Wt2s: 512 KiB
    //   v_ws: 256*512 fp32 (512 KiB)    | scores: 256*512 fp32 (512 KiB)
    ushort* Wt1s   = (ushort*)d_ws;
    ushort* Wt2s   = Wt1s + 16 * KSTR;
    float*  v_ws   = (float*)(Wt2s + 16 * KSTR);
    float*  scores = v_ws + BB * HID;

    convert_swz<<<dim3(16, 8), 256, 0, stream>>>(W1, Wt1s);
    convert_swz<<<dim3(16, 8), 256, 0, stream>>>(W2, Wt2s);
    base_kernel<<<BB, 256, 0, stream>>>(nodes_hv, class_cond, W1, b1,
                                        dirns, node_counts, v_ws);
    mlp2<<<dim3(NMAX / MT, BB), 256, 0, stream>>>(
        nodes_hv, Wt1s, Wt2s, b2, W3, b3, dirns, node_counts, v_ws, scores);
    loss_kernel<<<BB, 256, 0, stream>>>(scores, dests, out);
}

// Round 5
// 352.562 us; speedup vs baseline: 4.9413x; 1.0092x over previous
//
#include <hip/hip_runtime.h>
#include <math.h>

// Problem constants
#define BB    256
#define NMAX  512
#define HH    256   // H
#define CC    64    // C
#define HID   512
#define NEGV  -1000000000.0f
#define MT    32    // d-rows per mlp block
#define SA_LD 264   // 256 + 8 pad (bf16 elems)
#define SH_LD 520   // 512 + 8 pad
#define TILE  512   // ushorts per swizzled (16n x 32k) tile = 1KB
#define KSTR  (32 * TILE)  // ushorts per kb slab (32 n-tiles)

typedef __attribute__((ext_vector_type(8))) short short8;   // 8 bf16 = 4 VGPRs
typedef __attribute__((ext_vector_type(4))) float floatx4;  // MFMA C/D

__device__ inline ushort f2bf(float x) {
    unsigned u = __float_as_uint(x);
    u = (u + 0x7FFFu + ((u >> 16) & 1u)) >> 16;   // RNE
    return (ushort)u;
}

// ---------------------------------------------------------------------------
// Fused prep kernel, grid = 512 blocks x 256 threads:
//   blocks [0,128):   convert W1 k-rows [0,512) -> swizzled lane-order bf16
//   blocks [128,256): convert W2 -> swizzled lane-order bf16
//   blocks [256,512): per-batch base vector v_b (fp32 exact)
// All three parts are independent (read only inputs). Block-uniform branch.
// ---------------------------------------------------------------------------
__global__ __launch_bounds__(256) void prep_kernel(
    const float* __restrict__ W1, const float* __restrict__ W2,
    ushort* __restrict__ Wt1s, ushort* __restrict__ Wt2s,
    const float* __restrict__ nodes_hv, const float* __restrict__ class_cond,
    const float* __restrict__ b1,
    const int* __restrict__ dirns, const int* __restrict__ node_counts,
    float* __restrict__ v_ws)
{
    const int blk = blockIdx.x;
    const int t = threadIdx.x;

    __shared__ float s_conv[32][68];   // convert path: 32 k-rows x 64 n (+4 pad)
    __shared__ float s_src[HH];        // base path
    __shared__ float s_cc[CC];

    if (blk < 256) {
        // ---------------- convert path ----------------
        const float* W = (blk < 128) ? W1 : W2;
        ushort* out    = (blk < 128) ? Wt1s : Wt2s;
        const int bb  = blk & 127;
        const int kb  = bb >> 3, ntg = bb & 7;   // 16 kb x 8 ntg

        {
            const int kl = t >> 3, nn = (t & 7) * 8;
            const float* src = W + (size_t)(kb * 32 + kl) * HID + ntg * 64 + nn;
            *(float4*)&s_conv[kl][nn]     = *(const float4*)src;
            *(float4*)&s_conv[kl][nn + 4] = *(const float4*)(src + 4);
        }
        __syncthreads();

        const int ntl = t >> 6, ls = t & 63;
        const int qs = ls >> 4, l15s = ls & 15;
        short8 o;
        #pragma unroll
        for (int j = 0; j < 8; ++j)
            o[j] = (short)f2bf(s_conv[qs * 8 + j][ntl * 16 + l15s]);
        const int nt = ntg * 4 + ntl;
        *(short8*)(out + ((size_t)(kb * 32 + nt)) * TILE + ls * 8) = o;
    } else {
        // ---------------- base-vector path ----------------
        const int b = blk - 256;
        const int nc   = node_counts[b];
        const int dirn = dirns[b];
        const int src_idx = nc - 1;

        s_src[t] = nodes_hv[((size_t)b * NMAX + src_idx) * HH + t];
        if (t < CC) s_cc[t] = class_cond[b * CC + t];
        __syncthreads();

        const int srcoff = (dirn == 1) ? HH : 0;   // src rows of W1

        const int j = 2 * t;
        float acc0 = b1[j];
        float acc1 = b1[j + 1];

        #pragma unroll 4
        for (int r = 0; r < HH; ++r) {
            const float s = s_src[r];
            const float* wp = W1 + (size_t)(srcoff + r) * HID + j;
            acc0 += s * wp[0];
            acc1 += s * wp[1];
        }
        #pragma unroll 4
        for (int c = 0; c < CC; ++c) {
            const float s = s_cc[c];
            const float* wp = W1 + (size_t)(2 * HH + c) * HID + j;
            acc0 += s * wp[0];
            acc1 += s * wp[1];
        }
        v_ws[b * HID + j]     = acc0;
        v_ws[b * HID + j + 1] = acc1;
    }
}

// ---------------------------------------------------------------------------
// Kernel 2: MFMA MLP. grid = (NMAX/MT, B), block = 256 (4 waves).
// Wave wv owns N-chunk [wv*128, +128): 2 m-blocks x 8 n-tiles of 16x16x32.
// LDS: single union buffer — s_a (cand tile) is dead after layer 1, so the
// h1 tile reuses it (extra barrier). 33.8 KB total -> 4 blocks/CU.
// Plain per-K-step loads from lane-order swizzled weights; latency hidden by
// wave-level overlap. Compiler owns waitcnts (R3 showed manual cross-barrier
// register pipelines are replay-unstable).
// ---------------------------------------------------------------------------
__global__ __launch_bounds__(256, 4) void mlp2(
    const float* __restrict__ nodes_hv,
    const ushort* __restrict__ Wt1s, const ushort* __restrict__ Wt2s,
    const float* __restrict__ b2, const float* __restrict__ W3,
    const float* __restrict__ b3,
    const int* __restrict__ dirns, const int* __restrict__ node_counts,
    const float* __restrict__ v_ws, float* __restrict__ scores)
{
    const int b  = blockIdx.y;
    const int d0 = blockIdx.x * MT;
    const int t  = threadIdx.x;
    const int lane = t & 63, wv = t >> 6;
    const int l15 = lane & 15, q = lane >> 4;

    __shared__ ushort s_u[MT * SH_LD];     // union: cand tile then h1 tile (33.3 KB)
    __shared__ float  s_red[4][MT];

    const int nc = node_counts[b];
    // dirn==1: cand occupies x[0:256) -> W1 k-rows [0:256) -> kb0=0; else kb0=8
    const int kb0 = (dirns[b] == 1) ? 0 : 8;

    // ---- stage cand tile (MT x 256 fp32 -> bf16 LDS, leading dim SA_LD) ----
    {
        const float4* src4 = (const float4*)nodes_hv + ((size_t)b * NMAX + d0) * (HH / 4);
        #pragma unroll
        for (int i = 0; i < (MT * HH / 4) / 256; ++i) {   // 8 iters
            int idx = t + i * 256;
            int row = idx >> 6, c4 = idx & 63;
            float4 v = src4[idx];
            ushort4 p;
            p.x = f2bf(v.x); p.y = f2bf(v.y); p.z = f2bf(v.z); p.w = f2bf(v.w);
            *(ushort4*)&s_u[row * SA_LD + c4 * 4] = p;
        }
    }
    __syncthreads();

    floatx4 acc[2][8];
    #pragma unroll
    for (int mb = 0; mb < 2; ++mb)
        #pragma unroll
        for (int tn = 0; tn < 8; ++tn)
            acc[mb][tn] = (floatx4){0.f, 0.f, 0.f, 0.f};

    // ---- layer 1: K = 256 (8 K-steps of 32) ----
    {
        const ushort* wb1 = Wt1s + ((size_t)kb0 * 32 + wv * 8) * TILE + lane * 8;
        #pragma unroll
        for (int ks = 0; ks < 8; ++ks) {
            const ushort* wp = wb1 + (size_t)ks * KSTR;
            short8 bfr[8];
            #pragma unroll
            for (int tn = 0; tn < 8; ++tn)
                bfr[tn] = *(const short8*)(wp + tn * TILE);
            short8 a0 = *(const short8*)&s_u[l15 * SA_LD + ks * 32 + q * 8];
            short8 a1 = *(const short8*)&s_u[(16 + l15) * SA_LD + ks * 32 + q * 8];
            #pragma unroll
            for (int tn = 0; tn < 8; ++tn) {
                acc[0][tn] = __builtin_amdgcn_mfma_f32_16x16x32_bf16(a0, bfr[tn], acc[0][tn], 0, 0, 0);
                acc[1][tn] = __builtin_amdgcn_mfma_f32_16x16x32_bf16(a1, bfr[tn], acc[1][tn], 0, 0, 0);
            }
        }
    }
    __syncthreads();   // all waves done reading cand tile before h1 overwrites it

    const int n0 = wv * 128;

    // ---- epilogue 1: h1 = relu(acc + v_b) -> s_u (bf16, leading dim SH_LD) ----
    #pragma unroll
    for (int tn = 0; tn < 8; ++tn) {
        const int n = n0 + tn * 16 + l15;
        const float v = v_ws[b * HID + n];
        #pragma unroll
        for (int mb = 0; mb < 2; ++mb)
            #pragma unroll
            for (int r = 0; r < 4; ++r) {
                float h = acc[mb][tn][r] + v;          // C/D: row=q*4+r, col=l15
                h = h > 0.f ? h : 0.f;
                s_u[(mb * 16 + q * 4 + r) * SH_LD + n] = f2bf(h);
            }
    }
    __syncthreads();

    // ---- layer 2: K = 512 (16 K-steps) ----
    #pragma unroll
    for (int mb = 0; mb < 2; ++mb)
        #pragma unroll
        for (int tn = 0; tn < 8; ++tn)
            acc[mb][tn] = (floatx4){0.f, 0.f, 0.f, 0.f};
    {
        const ushort* wb2 = Wt2s + ((size_t)wv * 8) * TILE + lane * 8;
        #pragma unroll
        for (int ks = 0; ks < 16; ++ks) {
            const ushort* wp = wb2 + (size_t)ks * KSTR;
            short8 bfr[8];
            #pragma unroll
            for (int tn = 0; tn < 8; ++tn)
                bfr[tn] = *(const short8*)(wp + tn * TILE);
            short8 a0 = *(const short8*)&s_u[l15 * SH_LD + ks * 32 + q * 8];
            short8 a1 = *(const short8*)&s_u[(16 + l15) * SH_LD + ks * 32 + q * 8];
            #pragma unroll
            for (int tn = 0; tn < 8; ++tn) {
                acc[0][tn] = __builtin_amdgcn_mfma_f32_16x16x32_bf16(a0, bfr[tn], acc[0][tn], 0, 0, 0);
                acc[1][tn] = __builtin_amdgcn_mfma_f32_16x16x32_bf16(a1, bfr[tn], acc[1][tn], 0, 0, 0);
            }
        }
    }

    // ---- epilogue 2: p = relu(acc + b2) . W3, reduce over n ----
    float p[2][4] = {{0.f, 0.f, 0.f, 0.f}, {0.f, 0.f, 0.f, 0.f}};
    #pragma unroll
    for (int tn = 0; tn < 8; ++tn) {
        const int n  = n0 + tn * 16 + l15;
        const float bb = b2[n];
        const float w3 = W3[n];
        #pragma unroll
        for (int mb = 0; mb < 2; ++mb)
            #pragma unroll
            for (int r = 0; r < 4; ++r) {
                float h = acc[mb][tn][r] + bb;
                h = h > 0.f ? h : 0.f;
                p[mb][r] += h * w3;
            }
    }
    #pragma unroll
    for (int mb = 0; mb < 2; ++mb)
        #pragma unroll
        for (int r = 0; r < 4; ++r) {
            float v = p[mb][r];
            v += __shfl_xor(v, 1, 64);
            v += __shfl_xor(v, 2, 64);
            v += __shfl_xor(v, 4, 64);
            v += __shfl_xor(v, 8, 64);
            if (l15 == 0) s_red[wv][mb * 16 + q * 4 + r] = v;
        }
    __syncthreads();
    if (t < MT) {
        const float s = s_red[0][t] + s_red[1][t] + s_red[2][t] + s_red[3][t] + b3[0];
        const int d = d0 + t;
        scores[b * NMAX + d] = (d < nc - 1) ? s : NEGV;
    }
}

// ---------------------------------------------------------------------------
// Kernel 3: per-batch masked log-softmax NLL. grid = B, block = 256.
// ---------------------------------------------------------------------------
__global__ __launch_bounds__(256) void loss_kernel(
    const float* __restrict__ scores, const int* __restrict__ dests,
    float* __restrict__ out)
{
    const int b = blockIdx.x;
    const int t = threadIdx.x;
    __shared__ float red[4];

    const float s0 = scores[b * NMAX + t];
    const float s1 = scores[b * NMAX + t + 256];

    const int lane = t & 63, wv = t >> 6;

    float mx = fmaxf(s0, s1);
    #pragma unroll
    for (int off = 32; off > 0; off >>= 1) mx = fmaxf(mx, __shfl_down(mx, off, 64));
    if (lane == 0) red[wv] = mx;
    __syncthreads();
    mx = fmaxf(fmaxf(red[0], red[1]), fmaxf(red[2], red[3]));
    __syncthreads();

    float e = __expf(s0 - mx) + __expf(s1 - mx);
    #pragma unroll
    for (int off = 32; off > 0; off >>= 1) e += __shfl_down(e, off, 64);
    if (lane == 0) red[wv] = e;
    __syncthreads();

    if (t == 0) {
        const float sum = red[0] + red[1] + red[2] + red[3];
        const float sd = scores[b * NMAX + dests[b]];
        out[b] = -(sd - mx - logf(sum));
    }
}

// ---------------------------------------------------------------------------
extern "C" void kernel_launch(void* const* d_in, const int* in_sizes, int n_in,
                              void* d_out, int out_size, void* d_ws, size_t ws_size,
                              hipStream_t stream) {
    const float* nodes_hv    = (const float*)d_in[0];
    const float* class_cond  = (const float*)d_in[1];
    const float* W1          = (const float*)d_in[2];
    const float* b1          = (const float*)d_in[3];
    const float* W2          = (const float*)d_in[4];
    const float* b2          = (const float*)d_in[5];
    const float* W3          = (const float*)d_in[6];
    const float* b3          = (const float*)d_in[7];
    const int*   dirns       = (const int*)d_in[8];
    const int*   node_counts = (const int*)d_in[9];
    const int*   dests       = (const int*)d_in[10];
    float* out = (float*)d_out;

    // ws layout (16B-aligned):
    //   Wt1s: 512 tiles * 1KB (512 KiB) | Wt2s: 512 KiB
    //   v_ws: 256*512 fp32 (512 KiB)    | scores: 256*512 fp32 (512 KiB)
    ushort* Wt1s   = (ushort*)d_ws;
    ushort* Wt2s   = Wt1s + 16 * KSTR;
    float*  v_ws   = (float*)(Wt2s + 16 * KSTR);
    float*  scores = v_ws + BB * HID;

    prep_kernel<<<512, 256, 0, stream>>>(W1, W2, Wt1s, Wt2s,
                                         nodes_hv, class_cond, b1,
                                         dirns, node_counts, v_ws);
    mlp2<<<dim3(NMAX / MT, BB), 256, 0, stream>>>(
        nodes_hv, Wt1s, Wt2s, b2, W3, b3, dirns, node_counts, v_ws, scores);
    loss_kernel<<<BB, 256, 0, stream>>>(scores, dests, out);
}